// Round 5
// baseline (675.026 us; speedup 1.0000x reference)
//
#include <hip/hip_runtime.h>
#include <hip/hip_bf16.h>

typedef unsigned short u16;
typedef unsigned int u32;
typedef float f32x4 __attribute__((ext_vector_type(4)));
typedef __bf16 bf16x8 __attribute__((ext_vector_type(8)));

#define AS1 __attribute__((address_space(1)))
#define AS3 __attribute__((address_space(3)))

// ---- constants -------------------------------------------------------------
// M = B*T = 32768 tokens, D = 768, H = 2048
#define MTOT 32768
#define DK   768
#define HN   2048

// Octonion tables: Big[i*A+a][c*B+b] = S2[i][c] * w[J[i][c]][a][b]
__constant__ signed char J_TAB[64] = {
  0,1,2,3,4,5,6,7,
  1,0,3,2,5,4,7,6,
  2,3,0,1,6,7,4,5,
  3,2,1,0,7,6,5,4,
  4,5,6,7,0,1,2,3,
  5,4,7,6,1,0,3,2,
  6,7,4,5,2,3,0,1,
  7,6,5,4,3,2,1,0};
__constant__ signed char S_TAB[64] = {
   1, 1, 1, 1, 1, 1, 1, 1,
  -1, 1,-1, 1,-1, 1, 1,-1,
  -1, 1, 1,-1,-1,-1, 1, 1,
  -1,-1, 1, 1,-1, 1,-1, 1,
  -1, 1, 1, 1, 1,-1,-1,-1,
  -1,-1, 1,-1, 1, 1, 1,-1,
  -1,-1,-1, 1, 1,-1, 1, 1,
  -1, 1,-1,-1, 1, 1,-1, 1};

// ---- helpers ---------------------------------------------------------------
__device__ __forceinline__ u16 f2bf(float f) {  // RNE float->bf16
  u32 x = __float_as_uint(f);
  x += 0x7fffu + ((x >> 16) & 1u);
  return (u16)(x >> 16);
}

__device__ __forceinline__ void gload_lds16(const void* g, void* l) {
  // async global->LDS, 16B per lane; LDS dest = wave-uniform base + lane*16
  __builtin_amdgcn_global_load_lds((AS1 void*)(g), (AS3 void*)(l), 16, 0, 0);
}

// gemm1 (measured best R2): PINNED waits/barriers — sched_barrier sandwiches.
#define PVMW(N) do { __builtin_amdgcn_sched_barrier(0); \
  asm volatile("s_waitcnt vmcnt(" #N ")" ::: "memory"); \
  __builtin_amdgcn_sched_barrier(0); } while (0)
#define PBAR() do { __builtin_amdgcn_sched_barrier(0); \
  __builtin_amdgcn_s_barrier(); \
  __builtin_amdgcn_sched_barrier(0); } while (0)
// gemm2: unpinned (measured better there R4)
#define VMW(N) asm volatile("s_waitcnt vmcnt(" #N ")" ::: "memory")
#define BAR() __builtin_amdgcn_s_barrier()

// Stage one 128x64 bf16 half-tile (row-major, leading dim LDK) into contiguous
// LDS. 512 threads x 2 loads of 16B. XOR swizzle: global chunk c of row r lands
// at LDS slot c^(r&7)  (pre-swizzled global source + linear LDS dest).
template <int LDK>
__device__ __forceinline__ void stage_half(const u16* __restrict__ src,
                                           u16* lds, int tid) {
#pragma unroll
  for (int f0 = 0; f0 < 1024; f0 += 512) {
    int flat = f0 + tid;
    int row = flat >> 3;
    int c = (flat & 7) ^ (row & 7);
    gload_lds16(src + row * LDK + c * 8, lds + (f0 + (tid & ~63)) * 8);
  }
}

// ---- gemm1 K-tile (BK=64): 4 phases (R2-exact, pinned) ----------------------
template <int LDK, bool SA, bool SB, int VM>
__device__ __forceinline__ void ktile4(
    const u16* lAp, const u16* lBp, u16* lAn, u16* lBn,
    const u16* __restrict__ aStage, const u16* __restrict__ bStage,
    int tid, int arow, int brow, int c0, int c1, f32x4 (&acc)[8][4]) {
  bf16x8 a0[4], a1[4], a2[4], a3[4], b0[4], b1[4];
  // ---- phase 0: reads C0 then C1; stage A(S+1) h0
#pragma unroll
  for (int mi = 0; mi < 4; ++mi)
    a0[mi] = *(const bf16x8*)(lAp + (arow + mi * 16) * 64 + c0);
#pragma unroll
  for (int ni = 0; ni < 4; ++ni)
    b0[ni] = *(const bf16x8*)(lBp + (brow + ni * 16) * 64 + c0);
#pragma unroll
  for (int mi = 0; mi < 4; ++mi)
    a1[mi] = *(const bf16x8*)(lAp + (arow + mi * 16) * 64 + c1);
#pragma unroll
  for (int ni = 0; ni < 4; ++ni)
    b1[ni] = *(const bf16x8*)(lBp + (brow + ni * 16) * 64 + c1);
  if constexpr (SA) stage_half<LDK>(aStage, lAn, tid);
  PBAR();
  __builtin_amdgcn_s_setprio(1);
#pragma unroll
  for (int mi = 0; mi < 4; ++mi)
#pragma unroll
    for (int ni = 0; ni < 4; ++ni)
      acc[mi][ni] = __builtin_amdgcn_mfma_f32_16x16x32_bf16(
          a0[mi], b0[ni], acc[mi][ni], 0, 0, 0);
  __builtin_amdgcn_s_setprio(0);
  PBAR();
  // ---- phase 1: reads C2; stage A(S+1) h1
#pragma unroll
  for (int mi = 0; mi < 4; ++mi)
    a2[mi] = *(const bf16x8*)(lAp + (arow + 64 + mi * 16) * 64 + c0);
  if constexpr (SA) stage_half<LDK>(aStage + 128 * LDK, lAn + 128 * 64, tid);
  PBAR();
  __builtin_amdgcn_s_setprio(1);
#pragma unroll
  for (int mi = 0; mi < 4; ++mi)
#pragma unroll
    for (int ni = 0; ni < 4; ++ni)
      acc[mi][ni] = __builtin_amdgcn_mfma_f32_16x16x32_bf16(
          a1[mi], b1[ni], acc[mi][ni], 0, 0, 0);
  __builtin_amdgcn_s_setprio(0);
  PBAR();
  // ---- phase 2: reads C3; stage B(S+2) h0 (safe: B reads completed ph0/ph1)
#pragma unroll
  for (int mi = 0; mi < 4; ++mi)
    a3[mi] = *(const bf16x8*)(lAp + (arow + 64 + mi * 16) * 64 + c1);
  if constexpr (SB) stage_half<LDK>(bStage, lBn, tid);
  PBAR();
  __builtin_amdgcn_s_setprio(1);
#pragma unroll
  for (int mi = 0; mi < 4; ++mi)
#pragma unroll
    for (int ni = 0; ni < 4; ++ni)
      acc[4 + mi][ni] = __builtin_amdgcn_mfma_f32_16x16x32_bf16(
          a2[mi], b0[ni], acc[4 + mi][ni], 0, 0, 0);
  __builtin_amdgcn_s_setprio(0);
  PBAR();
  // ---- phase 3: stage B(S+2) h1; counted vmcnt retires A(S+1)+B(S+1)
  if constexpr (SB) stage_half<LDK>(bStage + 128 * LDK, lBn + 128 * 64, tid);
  if constexpr (VM == 4) PVMW(4);
  else if constexpr (VM == 0) PVMW(0);
  PBAR();
  __builtin_amdgcn_s_setprio(1);
#pragma unroll
  for (int mi = 0; mi < 4; ++mi)
#pragma unroll
    for (int ni = 0; ni < 4; ++ni)
      acc[4 + mi][ni] = __builtin_amdgcn_mfma_f32_16x16x32_bf16(
          a3[mi], b1[ni], acc[4 + mi][ni], 0, 0, 0);
  __builtin_amdgcn_s_setprio(0);
  PBAR();
}

// ---- 256x256 pipelined GEMM core (gemm1), NK K-tiles of 64 (NK even) --------
template <int NK, int LDK>
__device__ __forceinline__ void gemm_core(const u16* __restrict__ aSrc,
                                          const u16* __restrict__ bSrc, int tid,
                                          u16* lA0, u16* lA1, u16* lB0, u16* lB1,
                                          f32x4 (&acc)[8][4]) {
  const int lane = tid & 63;
  const int wave = tid >> 6;
  const int wm = wave >> 2, wn = wave & 3;
  const int l15 = lane & 15, quad = (lane >> 4) & 3;
  const int arow = wm * 128 + l15;
  const int brow = wn * 64 + l15;
  const int c0 = (quad ^ (l15 & 7)) * 8;
  const int c1 = ((quad + 4) ^ (l15 & 7)) * 8;

  // prologue: K-tile0 (A,B) + B of K-tile1; vmcnt(4) leaves B(1) in flight
  stage_half<LDK>(aSrc, lA0, tid);
  stage_half<LDK>(aSrc + 128 * LDK, lA0 + 128 * 64, tid);
  stage_half<LDK>(bSrc, lB0, tid);
  stage_half<LDK>(bSrc + 128 * LDK, lB0 + 128 * 64, tid);
  stage_half<LDK>(bSrc + 64, lB1, tid);
  stage_half<LDK>(bSrc + 64 + 128 * LDK, lB1 + 128 * 64, tid);
  PVMW(4);
  PBAR();

#pragma unroll 1
  for (int i = 0; i < NK / 2 - 1; ++i) {
    ktile4<LDK, true, true, 4>(lA0, lB0, lA1, lB0,
                               aSrc + (2 * i + 1) * 64, bSrc + (2 * i + 2) * 64,
                               tid, arow, brow, c0, c1, acc);
    ktile4<LDK, true, true, 4>(lA1, lB1, lA0, lB1,
                               aSrc + (2 * i + 2) * 64, bSrc + (2 * i + 3) * 64,
                               tid, arow, brow, c0, c1, acc);
  }
  ktile4<LDK, true, false, 0>(lA0, lB0, lA1, lB0,
                              aSrc + (NK - 1) * 64, nullptr,
                              tid, arow, brow, c0, c1, acc);
  ktile4<LDK, false, false, -1>(lA1, lB1, lA0, lB1, nullptr, nullptr,
                                tid, arow, brow, c0, c1, acc);
}

// ---- gemm2 building blocks --------------------------------------------------
// B-tile 256(N-rows of Big^T) x 32(K): stage with 256 threads, 4 gload_lds.
// Swizzle sw3: chunk c of row r lives at slot c ^ sw3(r)  (2-way max conflict
// on the b128 fragment reads).
__device__ __forceinline__ int sw3(int r) { return (r ^ (r >> 2)) & 3; }

__device__ __forceinline__ void stage_b32(const u16* __restrict__ src,
                                          u16* lds, int tid) {
#pragma unroll
  for (int f0 = 0; f0 < 1024; f0 += 256) {
    int flat = f0 + tid;
    int row = flat >> 2;
    int c = (flat & 3) ^ sw3(row);
    gload_lds16(src + (size_t)row * HN + c * 8, lds + (f0 + (tid & ~63)) * 8);
  }
}

// One gemm2 K-tile (BK=32): read B(T) frags from lBread; stage B(T+2) to
// lBwrite (a buffer nobody reads this or next ktile); issue A(T+1) global->reg
// into aNxt; 16 MFMA on aCur; counted vmcnt; barrier. A never touches LDS.
template <bool STG, bool ANXT, int VM>
__device__ __forceinline__ void ktile_g2(
    const u16* lBread, u16* lBwrite,
    const u16* __restrict__ bStage, const u16* __restrict__ aNxtSrc,
    bf16x8 (&aCur)[4], bf16x8 (&aNxt)[4],
    int tid, int brow, int quad, f32x4 (&acc)[4][4]) {
  bf16x8 bf[4];
#pragma unroll
  for (int ni = 0; ni < 4; ++ni) {
    int row = brow + ni * 16;
    bf[ni] = *(const bf16x8*)(lBread + row * 32 + (quad ^ sw3(row)) * 8);
  }
  if constexpr (STG) stage_b32(bStage, lBwrite, tid);
  if constexpr (ANXT) {
#pragma unroll
    for (int mi = 0; mi < 4; ++mi)
      aNxt[mi] = *(const bf16x8*)(aNxtSrc + (size_t)mi * 16 * HN);
  }
  __builtin_amdgcn_s_setprio(1);
#pragma unroll
  for (int mi = 0; mi < 4; ++mi)
#pragma unroll
    for (int ni = 0; ni < 4; ++ni)
      acc[mi][ni] = __builtin_amdgcn_mfma_f32_16x16x32_bf16(
          aCur[mi], bf[ni], acc[mi][ni], 0, 0, 0);
  __builtin_amdgcn_s_setprio(0);
  if constexpr (VM == 8) VMW(8);
  else if constexpr (VM == 0) VMW(0);
  BAR();
}

// ---- prep kernels ----------------------------------------------------------
__global__ void scales1_kernel(const float* __restrict__ w0,
                               const float* __restrict__ w1,
                               const float* __restrict__ w2,
                               float* __restrict__ partials) {
  __shared__ float red[256];
  const int t = blockIdx.x / 192;      // tensor id
  const int chunk = blockIdx.x % 192;  // 1024-float chunk
  const float* w = (t == 0) ? w0 : (t == 1) ? w1 : w2;
  const float4* w4 = (const float4*)(w + chunk * 1024);
  float4 v = w4[threadIdx.x];
  red[threadIdx.x] = fabsf(v.x) + fabsf(v.y) + fabsf(v.z) + fabsf(v.w);
  __syncthreads();
  for (int off = 128; off; off >>= 1) {
    if (threadIdx.x < off) red[threadIdx.x] += red[threadIdx.x + off];
    __syncthreads();
  }
  if (threadIdx.x == 0) partials[blockIdx.x] = red[0];
}

__global__ void scales2_kernel(const float* __restrict__ partials,
                               float* __restrict__ scales) {
  __shared__ float red[256];
  float s = (threadIdx.x < 192) ? partials[blockIdx.x * 192 + threadIdx.x] : 0.f;
  red[threadIdx.x] = s;
  __syncthreads();
  for (int off = 128; off; off >>= 1) {
    if (threadIdx.x < off) red[threadIdx.x] += red[threadIdx.x + off];
    __syncthreads();
  }
  if (threadIdx.x == 0) scales[blockIdx.x] = red[0] / 196608.f + 1e-8f;
}

// Build Big^T rows ({-1,0,+1} as bf16; absmean scale folded into epilogues).
// ilv 0/1 : gate/up interleaved at 16-col granularity into B_cat [4096 x 768]
// ilv -2  : w_down with k-index permuted by phi (h physical column layout):
//           phi(k) = (k&~31) | ((k&15)<<1) | ((k>>4)&1)
__global__ void build_big_kernel(const float* __restrict__ w,
                                 const float* __restrict__ scales, int sidx,
                                 int A, int B, int ilv, u16* __restrict__ dst) {
  int idx = blockIdx.x * 256 + threadIdx.x;  // n*K8 + k, exact grid
  int K8 = 8 * A;
  int n = idx / K8;
  int k = idx - n * K8;
  int i = k / A, a = k - i * A;
  int c = n / B, b = n - c * B;
  float scale = scales[sidx];
  int j = J_TAB[i * 8 + c];
  float q = rintf(w[(j * A + a) * B + b] / scale);
  q = fminf(1.f, fmaxf(-1.f, q));
  int nd = (ilv >= 0) ? (((n & ~15) << 1) | (ilv << 4) | (n & 15)) : n;
  int kd = (ilv == -2) ? ((k & ~31) | ((k & 15) << 1) | ((k >> 4) & 1)) : k;
  dst[nd * K8 + kd] = f2bf(q * (float)S_TAB[i * 8 + c]);
}

__global__ void cvt_x_kernel(const float* __restrict__ x, u16* __restrict__ xb) {
  int gid = blockIdx.x * 256 + threadIdx.x;  // 8 floats per thread
  const float4* x4 = (const float4*)x;
  float4 v0 = x4[gid * 2], v1 = x4[gid * 2 + 1];
  uint4 o;
  o.x = (u32)f2bf(v0.x) | ((u32)f2bf(v0.y) << 16);
  o.y = (u32)f2bf(v0.z) | ((u32)f2bf(v0.w) << 16);
  o.z = (u32)f2bf(v1.x) | ((u32)f2bf(v1.y) << 16);
  o.w = (u32)f2bf(v1.z) | ((u32)f2bf(v1.w) << 16);
  ((uint4*)xb)[gid] = o;
}

// ---- GEMM1: [M x 768] @ B_cat[4096 x 768]^T -> SiLU(g)*u -> h bf16 [M x 2048]
// h columns stored permuted by phi; epilogue packs (pr0,pr1) into one u32.
__global__ __launch_bounds__(512, 2) void gemm1_kernel(
    const u16* __restrict__ xb, const u16* __restrict__ wgu,
    const float* __restrict__ scales, u16* __restrict__ h) {
  __shared__ __align__(16) u16 lA0[256 * 64], lA1[256 * 64];
  __shared__ __align__(16) u16 lB0[256 * 64], lB1[256 * 64];
  const int tid = threadIdx.x;
  const int logical = (blockIdx.x & 7) * 256 + (blockIdx.x >> 3);
  const int bn = logical & 15;   // 16 N_cat-tiles (fast: A-tile L2 reuse)
  const int bm = logical >> 4;   // 128 M-tiles
  const int m0 = bm * 256, n0 = bn * 256;

  f32x4 acc[8][4] = {};
  gemm_core<12, DK>(xb + (size_t)m0 * DK, wgu + (size_t)n0 * DK, tid,
                    lA0, lA1, lB0, lB1, acc);

  const int lane = tid & 63, wave = tid >> 6;
  const int wm = wave >> 2, wn = wave & 3;
  const int l15 = lane & 15, quad = lane >> 4;
  const float sg = scales[0], su = scales[1];
  const int a_ = bn * 4 + wn;            // 32-col physical group index
  u32* h32 = (u32*)h;
#pragma unroll
  for (int mi = 0; mi < 8; ++mi)
#pragma unroll
    for (int r = 0; r < 4; ++r) {
      int m = m0 + wm * 128 + mi * 16 + quad * 4 + r;
      float g0 = acc[mi][0][r] * sg, u0 = acc[mi][1][r] * su;
      float g1 = acc[mi][2][r] * sg, u1 = acc[mi][3][r] * su;
      float h0 = g0 / (1.f + __expf(-g0)) * u0;
      float h1 = g1 / (1.f + __expf(-g1)) * u1;
      h32[(size_t)m * (HN / 2) + a_ * 16 + l15] =
          (u32)f2bf(h0) | ((u32)f2bf(h1) << 16);
    }
}

// ---- GEMM2: [M x 2048] @ BigD -> out fp32 [M x 768] ------------------------
// 64(M) x 256(N), 256 threads / 4 waves (wave 64x64). A (h) fragments loaded
// DIRECTLY global->VGPR (16B contiguous per lane, 1 ktile ahead, compiler-
// paced) -- no A-LDS, no A-barrier coupling. B (wd, L2-resident) through
// triple-buffered LDS (48 KiB), staged 2 ktiles ahead, one barrier per ktile.
// 2 blocks/CU co-resident absorb stalls (m97 mechanism). Grid 1536 = 3 rounds.
__global__ __launch_bounds__(256, 2) void gemm2_kernel(
    const u16* __restrict__ h, const u16* __restrict__ wd,
    const float* __restrict__ scales, float* __restrict__ out) {
  __shared__ __align__(16) u16 lB[3][256 * 32];
  const int tid = threadIdx.x;
  // bijective XCD-chunked swizzle (1536 % 8 == 0); bn fastest: the 3 sharers
  // of one h-panel are bid-adjacent on one XCD.
  const int logical = (blockIdx.x & 7) * 192 + (blockIdx.x >> 3);
  const int bn = logical % 3;    // 3 N-tiles of 256
  const int bm = logical / 3;    // 512 M-tiles of 64
  const int m0 = bm * 64, n0 = bn * 256;

  const int lane = tid & 63, wave = tid >> 6;
  const int l15 = lane & 15, quad = (lane >> 4) & 3;
  const int brow = wave * 64 + l15;
  const u16* bSrc = wd + (size_t)n0 * HN;                 // + kt*32 per tile
  const u16* aBase = h + (size_t)(m0 + l15) * HN + quad * 8;  // + mi*16*HN + kt*32

  f32x4 acc[4][4] = {};
  bf16x8 aA[4], aB[4];

  // prologue: B(0)->lB0, B(1)->lB1, A(0)->aA; retire B(0) (leave B(1)+A(0))
  stage_b32(bSrc, lB[0], tid);
  stage_b32(bSrc + 32, lB[1], tid);
#pragma unroll
  for (int mi = 0; mi < 4; ++mi)
    aA[mi] = *(const bf16x8*)(aBase + (size_t)mi * 16 * HN);
  VMW(8);
  BAR();

  u16 *q0 = lB[0], *q1 = lB[1], *q2 = lB[2];
  // invariant at loop top: q0 = B(T), q1 = B(T+1), q2 = free (stage B(T+2))
#pragma unroll 1
  for (int it = 0; it < 31; ++it) {
    const int T = 2 * it;
    // ktile T   (aCur=aA): stage B(T+2)->q2, load A(T+1)->aB
    ktile_g2<true, true, 8>(q0, q2, bSrc + (T + 2) * 32,
                            aBase + (T + 1) * 32, aA, aB, tid, brow, quad, acc);
    // ktile T+1 (aCur=aB): stage B(T+3)->q0 (q0's reads done at T's barrier),
    // load A(T+2)->aA
    ktile_g2<true, true, 8>(q1, q0, bSrc + (T + 3) * 32,
                            aBase + (T + 2) * 32, aB, aA, tid, brow, quad, acc);
    u16* t = q0; q0 = q2; q2 = q1; q1 = t;  // (q0,q1,q2) <- (q2,q0,q1)
  }
  // T=62 (aCur=aA): no stage; load A(63)->aB; vmcnt(8) retires B(63)
  ktile_g2<false, true, 8>(q0, nullptr, nullptr, aBase + 63 * 32,
                           aA, aB, tid, brow, quad, acc);
  // T=63 (aCur=aB): pure compute
  ktile_g2<false, false, -1>(q1, nullptr, nullptr, nullptr,
                             aB, aA, tid, brow, quad, acc);

  const float sd = scales[2];
#pragma unroll
  for (int mi = 0; mi < 4; ++mi)
#pragma unroll
    for (int ni = 0; ni < 4; ++ni) {
      const int n = n0 + wave * 64 + ni * 16 + l15;
#pragma unroll
      for (int r = 0; r < 4; ++r) {
        int m = m0 + mi * 16 + quad * 4 + r;
        out[(size_t)m * DK + n] = acc[mi][ni][r] * sd;
      }
    }
}

// ---- launch ----------------------------------------------------------------
extern "C" void kernel_launch(void* const* d_in, const int* in_sizes, int n_in,
                              void* d_out, int out_size, void* d_ws, size_t ws_size,
                              hipStream_t stream) {
  const float* x      = (const float*)d_in[0];
  const float* w_gate = (const float*)d_in[1];
  const float* w_up   = (const float*)d_in[2];
  const float* w_down = (const float*)d_in[3];
  float* out = (float*)d_out;

  // workspace layout (bytes):
  //  scales[3] @0 | partials[576] @256 | B_cat 6MB @4096 | BigD^T 3MB |
  //  xb 50MB | h 134MB
  char* ws = (char*)d_ws;
  float* scales   = (float*)ws;
  float* partials = (float*)(ws + 256);
  u16* wgu = (u16*)(ws + 4096);
  u16* wd  = (u16*)(ws + 4096 + 6291456u);
  u16* xb  = (u16*)(ws + 4096 + 9437184u);
  u16* h   = (u16*)(ws + 4096 + 9437184u + 50331648u);

  scales1_kernel<<<576, 256, 0, stream>>>(w_gate, w_up, w_down, partials);
  scales2_kernel<<<3, 256, 0, stream>>>(partials, scales);
  build_big_kernel<<<6144, 256, 0, stream>>>(w_gate, scales, 0, 96, 256, 0, wgu);
  build_big_kernel<<<6144, 256, 0, stream>>>(w_up,   scales, 1, 96, 256, 1, wgu);
  build_big_kernel<<<6144, 256, 0, stream>>>(w_down, scales, 2, 256, 96, -2, wd);
  cvt_x_kernel<<<12288, 256, 0, stream>>>(x, xb);
  gemm1_kernel<<<2048, 512, 0, stream>>>(xb, wgu, scales, h);
  gemm2_kernel<<<1536, 256, 0, stream>>>(h, wd, scales, out);
}

// Round 6
// 565.354 us; speedup vs baseline: 1.1940x; 1.1940x over previous
//
#include <hip/hip_runtime.h>
#include <hip/hip_bf16.h>

typedef unsigned short u16;
typedef unsigned int u32;
typedef float f32x4 __attribute__((ext_vector_type(4)));
typedef __bf16 bf16x8 __attribute__((ext_vector_type(8)));

#define AS1 __attribute__((address_space(1)))
#define AS3 __attribute__((address_space(3)))

// ---- constants -------------------------------------------------------------
// M = B*T = 32768 tokens, D = 768, H = 2048
#define MTOT 32768
#define DK   768
#define HN   2048

// Octonion tables: Big[i*A+a][c*B+b] = S2[i][c] * w[J[i][c]][a][b]
__constant__ signed char J_TAB[64] = {
  0,1,2,3,4,5,6,7,
  1,0,3,2,5,4,7,6,
  2,3,0,1,6,7,4,5,
  3,2,1,0,7,6,5,4,
  4,5,6,7,0,1,2,3,
  5,4,7,6,1,0,3,2,
  6,7,4,5,2,3,0,1,
  7,6,5,4,3,2,1,0};
__constant__ signed char S_TAB[64] = {
   1, 1, 1, 1, 1, 1, 1, 1,
  -1, 1,-1, 1,-1, 1, 1,-1,
  -1, 1, 1,-1,-1,-1, 1, 1,
  -1,-1, 1, 1,-1, 1,-1, 1,
  -1, 1, 1, 1, 1,-1,-1,-1,
  -1,-1, 1,-1, 1, 1, 1,-1,
  -1,-1,-1, 1, 1,-1, 1, 1,
  -1, 1,-1,-1, 1, 1,-1, 1};

// ---- helpers ---------------------------------------------------------------
__device__ __forceinline__ u16 f2bf(float f) {  // RNE float->bf16
  u32 x = __float_as_uint(f);
  x += 0x7fffu + ((x >> 16) & 1u);
  return (u16)(x >> 16);
}

__device__ __forceinline__ void gload_lds16(const void* g, void* l) {
  // async global->LDS, 16B per lane; LDS dest = wave-uniform base + lane*16
  __builtin_amdgcn_global_load_lds((AS1 void*)(g), (AS3 void*)(l), 16, 0, 0);
}

// gemm1 (measured best R2): PINNED waits/barriers — sched_barrier sandwiches.
#define PVMW(N) do { __builtin_amdgcn_sched_barrier(0); \
  asm volatile("s_waitcnt vmcnt(" #N ")" ::: "memory"); \
  __builtin_amdgcn_sched_barrier(0); } while (0)
#define PBAR() do { __builtin_amdgcn_sched_barrier(0); \
  __builtin_amdgcn_s_barrier(); \
  __builtin_amdgcn_sched_barrier(0); } while (0)

// Stage one 128x64 bf16 half-tile (row-major, leading dim LDK) into contiguous
// LDS. 512 threads x 2 loads of 16B. XOR swizzle: global chunk c of row r lands
// at LDS slot c^(r&7)  (pre-swizzled global source + linear LDS dest).
template <int LDK>
__device__ __forceinline__ void stage_half(const u16* __restrict__ src,
                                           u16* lds, int tid) {
#pragma unroll
  for (int f0 = 0; f0 < 1024; f0 += 512) {
    int flat = f0 + tid;
    int row = flat >> 3;
    int c = (flat & 7) ^ (row & 7);
    gload_lds16(src + row * LDK + c * 8, lds + (f0 + (tid & ~63)) * 8);
  }
}

// Stage 128x64 bf16 tile with 256 threads (gemm2, m97-style). Same XOR swizzle.
template <int LDK>
__device__ __forceinline__ void stage_tile256(const u16* __restrict__ src,
                                              u16* lds, int tid) {
#pragma unroll
  for (int f0 = 0; f0 < 1024; f0 += 256) {
    int flat = f0 + tid;
    int row = flat >> 3;
    int c = (flat & 7) ^ (row & 7);
    gload_lds16(src + (size_t)row * LDK + c * 8, lds + (f0 + (tid & 192)) * 8);
  }
}

// ---- gemm1 K-tile (BK=64): 4 phases (R2-exact, pinned) ----------------------
template <int LDK, bool SA, bool SB, int VM>
__device__ __forceinline__ void ktile4(
    const u16* lAp, const u16* lBp, u16* lAn, u16* lBn,
    const u16* __restrict__ aStage, const u16* __restrict__ bStage,
    int tid, int arow, int brow, int c0, int c1, f32x4 (&acc)[8][4]) {
  bf16x8 a0[4], a1[4], a2[4], a3[4], b0[4], b1[4];
  // ---- phase 0: reads C0 then C1; stage A(S+1) h0
#pragma unroll
  for (int mi = 0; mi < 4; ++mi)
    a0[mi] = *(const bf16x8*)(lAp + (arow + mi * 16) * 64 + c0);
#pragma unroll
  for (int ni = 0; ni < 4; ++ni)
    b0[ni] = *(const bf16x8*)(lBp + (brow + ni * 16) * 64 + c0);
#pragma unroll
  for (int mi = 0; mi < 4; ++mi)
    a1[mi] = *(const bf16x8*)(lAp + (arow + mi * 16) * 64 + c1);
#pragma unroll
  for (int ni = 0; ni < 4; ++ni)
    b1[ni] = *(const bf16x8*)(lBp + (brow + ni * 16) * 64 + c1);
  if constexpr (SA) stage_half<LDK>(aStage, lAn, tid);
  PBAR();
  __builtin_amdgcn_s_setprio(1);
#pragma unroll
  for (int mi = 0; mi < 4; ++mi)
#pragma unroll
    for (int ni = 0; ni < 4; ++ni)
      acc[mi][ni] = __builtin_amdgcn_mfma_f32_16x16x32_bf16(
          a0[mi], b0[ni], acc[mi][ni], 0, 0, 0);
  __builtin_amdgcn_s_setprio(0);
  PBAR();
  // ---- phase 1: reads C2; stage A(S+1) h1
#pragma unroll
  for (int mi = 0; mi < 4; ++mi)
    a2[mi] = *(const bf16x8*)(lAp + (arow + 64 + mi * 16) * 64 + c0);
  if constexpr (SA) stage_half<LDK>(aStage + 128 * LDK, lAn + 128 * 64, tid);
  PBAR();
  __builtin_amdgcn_s_setprio(1);
#pragma unroll
  for (int mi = 0; mi < 4; ++mi)
#pragma unroll
    for (int ni = 0; ni < 4; ++ni)
      acc[mi][ni] = __builtin_amdgcn_mfma_f32_16x16x32_bf16(
          a1[mi], b1[ni], acc[mi][ni], 0, 0, 0);
  __builtin_amdgcn_s_setprio(0);
  PBAR();
  // ---- phase 2: reads C3; stage B(S+2) h0 (safe: B reads completed ph0/ph1)
#pragma unroll
  for (int mi = 0; mi < 4; ++mi)
    a3[mi] = *(const bf16x8*)(lAp + (arow + 64 + mi * 16) * 64 + c1);
  if constexpr (SB) stage_half<LDK>(bStage, lBn, tid);
  PBAR();
  __builtin_amdgcn_s_setprio(1);
#pragma unroll
  for (int mi = 0; mi < 4; ++mi)
#pragma unroll
    for (int ni = 0; ni < 4; ++ni)
      acc[4 + mi][ni] = __builtin_amdgcn_mfma_f32_16x16x32_bf16(
          a2[mi], b0[ni], acc[4 + mi][ni], 0, 0, 0);
  __builtin_amdgcn_s_setprio(0);
  PBAR();
  // ---- phase 3: stage B(S+2) h1; counted vmcnt retires A(S+1)+B(S+1)
  if constexpr (SB) stage_half<LDK>(bStage + 128 * LDK, lBn + 128 * 64, tid);
  if constexpr (VM == 4) PVMW(4);
  else if constexpr (VM == 0) PVMW(0);
  PBAR();
  __builtin_amdgcn_s_setprio(1);
#pragma unroll
  for (int mi = 0; mi < 4; ++mi)
#pragma unroll
    for (int ni = 0; ni < 4; ++ni)
      acc[4 + mi][ni] = __builtin_amdgcn_mfma_f32_16x16x32_bf16(
          a3[mi], b1[ni], acc[4 + mi][ni], 0, 0, 0);
  __builtin_amdgcn_s_setprio(0);
  PBAR();
}

// ---- 256x256 pipelined GEMM core (gemm1), NK K-tiles of 64 (NK even) --------
template <int NK, int LDK>
__device__ __forceinline__ void gemm_core(const u16* __restrict__ aSrc,
                                          const u16* __restrict__ bSrc, int tid,
                                          u16* lA0, u16* lA1, u16* lB0, u16* lB1,
                                          f32x4 (&acc)[8][4]) {
  const int lane = tid & 63;
  const int wave = tid >> 6;
  const int wm = wave >> 2, wn = wave & 3;
  const int l15 = lane & 15, quad = (lane >> 4) & 3;
  const int arow = wm * 128 + l15;
  const int brow = wn * 64 + l15;
  const int c0 = (quad ^ (l15 & 7)) * 8;
  const int c1 = ((quad + 4) ^ (l15 & 7)) * 8;

  // prologue: K-tile0 (A,B) + B of K-tile1; vmcnt(4) leaves B(1) in flight
  stage_half<LDK>(aSrc, lA0, tid);
  stage_half<LDK>(aSrc + 128 * LDK, lA0 + 128 * 64, tid);
  stage_half<LDK>(bSrc, lB0, tid);
  stage_half<LDK>(bSrc + 128 * LDK, lB0 + 128 * 64, tid);
  stage_half<LDK>(bSrc + 64, lB1, tid);
  stage_half<LDK>(bSrc + 64 + 128 * LDK, lB1 + 128 * 64, tid);
  PVMW(4);
  PBAR();

#pragma unroll 1
  for (int i = 0; i < NK / 2 - 1; ++i) {
    ktile4<LDK, true, true, 4>(lA0, lB0, lA1, lB0,
                               aSrc + (2 * i + 1) * 64, bSrc + (2 * i + 2) * 64,
                               tid, arow, brow, c0, c1, acc);
    ktile4<LDK, true, true, 4>(lA1, lB1, lA0, lB1,
                               aSrc + (2 * i + 2) * 64, bSrc + (2 * i + 3) * 64,
                               tid, arow, brow, c0, c1, acc);
  }
  ktile4<LDK, true, false, 0>(lA0, lB0, lA1, lB0,
                              aSrc + (NK - 1) * 64, nullptr,
                              tid, arow, brow, c0, c1, acc);
  ktile4<LDK, false, false, -1>(lA1, lB1, lA0, lB1, nullptr, nullptr,
                                tid, arow, brow, c0, c1, acc);
}

// ---- prep kernels ----------------------------------------------------------
__global__ void scales1_kernel(const float* __restrict__ w0,
                               const float* __restrict__ w1,
                               const float* __restrict__ w2,
                               float* __restrict__ partials) {
  __shared__ float red[256];
  const int t = blockIdx.x / 192;      // tensor id
  const int chunk = blockIdx.x % 192;  // 1024-float chunk
  const float* w = (t == 0) ? w0 : (t == 1) ? w1 : w2;
  const float4* w4 = (const float4*)(w + chunk * 1024);
  float4 v = w4[threadIdx.x];
  red[threadIdx.x] = fabsf(v.x) + fabsf(v.y) + fabsf(v.z) + fabsf(v.w);
  __syncthreads();
  for (int off = 128; off; off >>= 1) {
    if (threadIdx.x < off) red[threadIdx.x] += red[threadIdx.x + off];
    __syncthreads();
  }
  if (threadIdx.x == 0) partials[blockIdx.x] = red[0];
}

__global__ void scales2_kernel(const float* __restrict__ partials,
                               float* __restrict__ scales) {
  __shared__ float red[256];
  float s = (threadIdx.x < 192) ? partials[blockIdx.x * 192 + threadIdx.x] : 0.f;
  red[threadIdx.x] = s;
  __syncthreads();
  for (int off = 128; off; off >>= 1) {
    if (threadIdx.x < off) red[threadIdx.x] += red[threadIdx.x + off];
    __syncthreads();
  }
  if (threadIdx.x == 0) scales[blockIdx.x] = red[0] / 196608.f + 1e-8f;
}

// Build Big^T rows ({-1,0,+1} as bf16; absmean scale folded into epilogues).
// ilv 0/1 : gate/up interleaved at 16-col granularity into B_cat [4096 x 768]
// ilv -2  : w_down with k-index permuted by phi (h physical column layout):
//           phi(k) = (k&~31) | ((k&15)<<1) | ((k>>4)&1)
__global__ void build_big_kernel(const float* __restrict__ w,
                                 const float* __restrict__ scales, int sidx,
                                 int A, int B, int ilv, u16* __restrict__ dst) {
  int idx = blockIdx.x * 256 + threadIdx.x;  // n*K8 + k, exact grid
  int K8 = 8 * A;
  int n = idx / K8;
  int k = idx - n * K8;
  int i = k / A, a = k - i * A;
  int c = n / B, b = n - c * B;
  float scale = scales[sidx];
  int j = J_TAB[i * 8 + c];
  float q = rintf(w[(j * A + a) * B + b] / scale);
  q = fminf(1.f, fmaxf(-1.f, q));
  int nd = (ilv >= 0) ? (((n & ~15) << 1) | (ilv << 4) | (n & 15)) : n;
  int kd = (ilv == -2) ? ((k & ~31) | ((k & 15) << 1) | ((k >> 4) & 1)) : k;
  dst[nd * K8 + kd] = f2bf(q * (float)S_TAB[i * 8 + c]);
}

__global__ void cvt_x_kernel(const float* __restrict__ x, u16* __restrict__ xb) {
  int gid = blockIdx.x * 256 + threadIdx.x;  // 8 floats per thread
  const float4* x4 = (const float4*)x;
  float4 v0 = x4[gid * 2], v1 = x4[gid * 2 + 1];
  uint4 o;
  o.x = (u32)f2bf(v0.x) | ((u32)f2bf(v0.y) << 16);
  o.y = (u32)f2bf(v0.z) | ((u32)f2bf(v0.w) << 16);
  o.z = (u32)f2bf(v1.x) | ((u32)f2bf(v1.y) << 16);
  o.w = (u32)f2bf(v1.z) | ((u32)f2bf(v1.w) << 16);
  ((uint4*)xb)[gid] = o;
}

// ---- GEMM1: [M x 768] @ B_cat[4096 x 768]^T -> SiLU(g)*u -> h bf16 [M x 2048]
// h columns stored permuted by phi; epilogue packs (pr0,pr1) into one u32.
__global__ __launch_bounds__(512, 2) void gemm1_kernel(
    const u16* __restrict__ xb, const u16* __restrict__ wgu,
    const float* __restrict__ scales, u16* __restrict__ h) {
  __shared__ __align__(16) u16 lA0[256 * 64], lA1[256 * 64];
  __shared__ __align__(16) u16 lB0[256 * 64], lB1[256 * 64];
  const int tid = threadIdx.x;
  const int logical = (blockIdx.x & 7) * 256 + (blockIdx.x >> 3);
  const int bn = logical & 15;   // 16 N_cat-tiles (fast: A-tile L2 reuse)
  const int bm = logical >> 4;   // 128 M-tiles
  const int m0 = bm * 256, n0 = bn * 256;

  f32x4 acc[8][4] = {};
  gemm_core<12, DK>(xb + (size_t)m0 * DK, wgu + (size_t)n0 * DK, tid,
                    lA0, lA1, lB0, lB1, acc);

  const int lane = tid & 63, wave = tid >> 6;
  const int wm = wave >> 2, wn = wave & 3;
  const int l15 = lane & 15, quad = lane >> 4;
  const float sg = scales[0], su = scales[1];
  const int a_ = bn * 4 + wn;            // 32-col physical group index
  u32* h32 = (u32*)h;
#pragma unroll
  for (int mi = 0; mi < 8; ++mi)
#pragma unroll
    for (int r = 0; r < 4; ++r) {
      int m = m0 + wm * 128 + mi * 16 + quad * 4 + r;
      float g0 = acc[mi][0][r] * sg, u0 = acc[mi][1][r] * su;
      float g1 = acc[mi][2][r] * sg, u1 = acc[mi][3][r] * su;
      float h0 = g0 / (1.f + __expf(-g0)) * u0;
      float h1 = g1 / (1.f + __expf(-g1)) * u1;
      h32[(size_t)m * (HN / 2) + a_ * 16 + l15] =
          (u32)f2bf(h0) | ((u32)f2bf(h1) << 16);
    }
}

// ---- GEMM2: [M x 2048] @ BigD -> out fp32 [M x 768] ------------------------
// m97-recipe (874-912 TF refcheck'd on this structure class): 128x128 tile,
// BK=64, 256 threads / 4 waves (wave 64x64), SINGLE-buffer 32 KiB LDS, plain
// 2-barrier loop, 3 blocks/CU -> inter-block overlap hides the barrier drain
// (m114 mechanism). Grid 1536 = 256 CU x 3 x 2 exact rounds.
__global__ __launch_bounds__(256, 3) void gemm2_kernel(
    const u16* __restrict__ h, const u16* __restrict__ wd,
    const float* __restrict__ scales, float* __restrict__ out) {
  __shared__ __align__(16) u16 lA[128 * 64];
  __shared__ __align__(16) u16 lB[128 * 64];
  const int tid = threadIdx.x;
  // bijective XCD-chunked swizzle (1536 % 8 == 0); bn fastest: the 6 wd
  // n-panels (3 MB total) stay L2-resident per XCD; h streamed once.
  const int logical = (blockIdx.x & 7) * 192 + (blockIdx.x >> 3);
  const int bn = logical % 6;    // 6 N-tiles of 128
  const int bm = logical / 6;    // 256 M-tiles of 128
  const int m0 = bm * 128, n0 = bn * 128;
  const u16* aSrc = h + (size_t)m0 * HN;
  const u16* bSrc = wd + (size_t)n0 * HN;

  const int lane = tid & 63, wave = tid >> 6;
  const int wm = wave >> 1, wn = wave & 1;
  const int l15 = lane & 15, quad = (lane >> 4) & 3;
  const int arow = wm * 64 + l15;
  const int brow = wn * 64 + l15;
  const int c0 = (quad ^ (l15 & 7)) * 8;
  const int c1 = ((quad + 4) ^ (l15 & 7)) * 8;

  f32x4 acc[4][4] = {};

#pragma unroll 1
  for (int S = 0; S < HN / 64; ++S) {
    stage_tile256<HN>(aSrc + S * 64, lA, tid);
    stage_tile256<HN>(bSrc + S * 64, lB, tid);
    __syncthreads();
#pragma unroll
    for (int k = 0; k < 2; ++k) {
      const int ck = k ? c1 : c0;
      bf16x8 af[4], bf[4];
#pragma unroll
      for (int mi = 0; mi < 4; ++mi)
        af[mi] = *(const bf16x8*)(lA + (arow + mi * 16) * 64 + ck);
#pragma unroll
      for (int ni = 0; ni < 4; ++ni)
        bf[ni] = *(const bf16x8*)(lB + (brow + ni * 16) * 64 + ck);
#pragma unroll
      for (int mi = 0; mi < 4; ++mi)
#pragma unroll
        for (int ni = 0; ni < 4; ++ni)
          acc[mi][ni] = __builtin_amdgcn_mfma_f32_16x16x32_bf16(
              af[mi], bf[ni], acc[mi][ni], 0, 0, 0);
    }
    __syncthreads();
  }

  const float sd = scales[2];
#pragma unroll
  for (int mi = 0; mi < 4; ++mi)
#pragma unroll
    for (int ni = 0; ni < 4; ++ni) {
      const int n = n0 + wn * 64 + ni * 16 + l15;
#pragma unroll
      for (int r = 0; r < 4; ++r) {
        int m = m0 + wm * 64 + mi * 16 + quad * 4 + r;
        out[(size_t)m * DK + n] = acc[mi][ni][r] * sd;
      }
    }
}

// ---- launch ----------------------------------------------------------------
extern "C" void kernel_launch(void* const* d_in, const int* in_sizes, int n_in,
                              void* d_out, int out_size, void* d_ws, size_t ws_size,
                              hipStream_t stream) {
  const float* x      = (const float*)d_in[0];
  const float* w_gate = (const float*)d_in[1];
  const float* w_up   = (const float*)d_in[2];
  const float* w_down = (const float*)d_in[3];
  float* out = (float*)d_out;

  // workspace layout (bytes):
  //  scales[3] @0 | partials[576] @256 | B_cat 6MB @4096 | BigD^T 3MB |
  //  xb 50MB | h 134MB
  char* ws = (char*)d_ws;
  float* scales   = (float*)ws;
  float* partials = (float*)(ws + 256);
  u16* wgu = (u16*)(ws + 4096);
  u16* wd  = (u16*)(ws + 4096 + 6291456u);
  u16* xb  = (u16*)(ws + 4096 + 9437184u);
  u16* h   = (u16*)(ws + 4096 + 9437184u + 50331648u);

  scales1_kernel<<<576, 256, 0, stream>>>(w_gate, w_up, w_down, partials);
  scales2_kernel<<<3, 256, 0, stream>>>(partials, scales);
  build_big_kernel<<<6144, 256, 0, stream>>>(w_gate, scales, 0, 96, 256, 0, wgu);
  build_big_kernel<<<6144, 256, 0, stream>>>(w_up,   scales, 1, 96, 256, 1, wgu);
  build_big_kernel<<<6144, 256, 0, stream>>>(w_down, scales, 2, 256, 96, -2, wd);
  cvt_x_kernel<<<12288, 256, 0, stream>>>(x, xb);
  gemm1_kernel<<<2048, 512, 0, stream>>>(xb, wgu, scales, h);
  gemm2_kernel<<<1536, 256, 0, stream>>>(h, wd, scales, out);
}